// Round 5
// baseline (148.677 us; speedup 1.0000x reference)
//
#include <hip/hip_runtime.h>

// out[b,i,j] = sum_f input[b,i,j,f] * theta[i,j,f]
// B=64, L=200, F=64.  input: [B, L*L, F] fp32, theta: [L*L, F] fp32,
// out: [B, L*L] fp32.
//
// Strategy (round 5): fix the scheduling tail. Round 3/4 launched 2500
// blocks over 2048 resident slots -> 1.22 rounds, 17% of traffic in a
// low-occupancy tail. Now: persistent 2048 blocks, grid-stride over 40000
// tiles (tile = 16 ij x 4 batches), 19-20 tiles/block (<=2.4% imbalance).
//  - tile id is chunk-major: 16 consecutive tiles share one chunk's theta
//    (4KB), active theta window ~512KB -> L2-resident; theta HBM ~10MB once.
//  - input loads non-temporal (evict-first) so the 655MB stream doesn't
//    displace theta in L2.
//  - 4 independent 16B NT loads in flight per thread per tile.
//  - 4-step __shfl_xor reduce within each 16-lane group.

#define BQ 64          // batch
#define LQ 200
#define FQ 64
#define IJ (LQ * LQ)   // 40000
#define EPB 16         // output elements per tile (256 threads / 16 lanes)
#define CHUNKS (IJ / EPB)      // 2500
#define TILES (CHUNKS * 16)    // 40000: (chunk, b-quad)
#define GRID 2048              // 256 CU x 8 blocks

typedef float f32x4 __attribute__((ext_vector_type(4)));

__global__ __launch_bounds__(256)
void IRLLinearModel_42786464203479_kernel(const float* __restrict__ inp,
                                          const float* __restrict__ theta,
                                          float* __restrict__ out) {
    const int g = threadIdx.x >> 4;   // element-within-chunk: 0..15
    const int s = threadIdx.x & 15;   // lane-within-group:    0..15
    const size_t bstride = (size_t)IJ * FQ;   // elements between batches

    #pragma unroll 1
    for (int tile = blockIdx.x; tile < TILES; tile += GRID) {
        const int chunk = tile >> 4;        // 0..2499
        const int b0    = (tile & 15) * 4;  // 0,4,...,60

        const int ij = chunk * EPB + g;     // < 40000

        // theta fragment (L2-hit after first visitor of this chunk)
        const f32x4 t = *reinterpret_cast<const f32x4*>(
            theta + (size_t)ij * FQ + (size_t)s * 4);

        const float* in_base = inp + (size_t)ij * FQ + (size_t)s * 4
                                   + (size_t)b0 * bstride;

        // 4 independent non-temporal loads in flight (independent of t-load)
        const f32x4 a0 = __builtin_nontemporal_load(
            reinterpret_cast<const f32x4*>(in_base + 0 * bstride));
        const f32x4 a1 = __builtin_nontemporal_load(
            reinterpret_cast<const f32x4*>(in_base + 1 * bstride));
        const f32x4 a2 = __builtin_nontemporal_load(
            reinterpret_cast<const f32x4*>(in_base + 2 * bstride));
        const f32x4 a3 = __builtin_nontemporal_load(
            reinterpret_cast<const f32x4*>(in_base + 3 * bstride));

        float p0 = a0.x * t.x + a0.y * t.y + a0.z * t.z + a0.w * t.w;
        float p1 = a1.x * t.x + a1.y * t.y + a1.z * t.z + a1.w * t.w;
        float p2 = a2.x * t.x + a2.y * t.y + a2.z * t.z + a2.w * t.w;
        float p3 = a3.x * t.x + a3.y * t.y + a3.z * t.z + a3.w * t.w;

        // reduce across the 16-lane group (masks < 16 stay inside the group)
        p0 += __shfl_xor(p0, 1);  p1 += __shfl_xor(p1, 1);
        p2 += __shfl_xor(p2, 1);  p3 += __shfl_xor(p3, 1);
        p0 += __shfl_xor(p0, 2);  p1 += __shfl_xor(p1, 2);
        p2 += __shfl_xor(p2, 2);  p3 += __shfl_xor(p3, 2);
        p0 += __shfl_xor(p0, 4);  p1 += __shfl_xor(p1, 4);
        p2 += __shfl_xor(p2, 4);  p3 += __shfl_xor(p3, 4);
        p0 += __shfl_xor(p0, 8);  p1 += __shfl_xor(p1, 8);
        p2 += __shfl_xor(p2, 8);  p3 += __shfl_xor(p3, 8);

        if (s == 0) {
            float* ob = out + (size_t)b0 * IJ + ij;
            __builtin_nontemporal_store(p0, ob + 0 * IJ);
            __builtin_nontemporal_store(p1, ob + 1 * IJ);
            __builtin_nontemporal_store(p2, ob + 2 * IJ);
            __builtin_nontemporal_store(p3, ob + 3 * IJ);
        }
    }
}

extern "C" void kernel_launch(void* const* d_in, const int* in_sizes, int n_in,
                              void* d_out, int out_size, void* d_ws, size_t ws_size,
                              hipStream_t stream) {
    const float* inp   = (const float*)d_in[0];
    const float* theta = (const float*)d_in[1];
    float* out = (float*)d_out;

    IRLLinearModel_42786464203479_kernel<<<GRID, 256, 0, stream>>>(inp, theta, out);
}

// Round 6
// 136.339 us; speedup vs baseline: 1.0905x; 1.0905x over previous
//
#include <hip/hip_runtime.h>

// out[b,i,j] = sum_f input[b,i,j,f] * theta[i,j,f]
// B=64, L=200, F=64.  input: [B, L*L, F] fp32, theta: [L*L, F] fp32,
// out: [B, L*L] fp32.
//
// Strategy (round 6): round-3 structure (block = chunk(s), theta in regs,
// 64-batch loop) with two fixes:
//  1. Software-pipelined b-loop: issue next quad's 4 NT loads BEFORE the
//     shuffle-reduce of the current quad -> loads always in flight (8 peak).
//  2. 2 chunks per block -> grid = 1250 (single scheduling round, no
//     452-block tail; theta still read once per chunk, outside the b-loop).

#define BQ 64          // batch
#define LQ 200
#define FQ 64
#define IJ (LQ * LQ)   // 40000
#define EPB 16         // output elements per chunk (256 threads / 16 lanes)
#define CPB 2          // chunks per block
#define GRID (IJ / (EPB * CPB))  // 1250

typedef float f32x4 __attribute__((ext_vector_type(4)));

#define NTLOAD(p) __builtin_nontemporal_load(reinterpret_cast<const f32x4*>(p))

__global__ __launch_bounds__(256)
void IRLLinearModel_42786464203479_kernel(const float* __restrict__ inp,
                                          const float* __restrict__ theta,
                                          float* __restrict__ out) {
    const int g = threadIdx.x >> 4;   // element-within-chunk: 0..15
    const int s = threadIdx.x & 15;   // lane-within-group:    0..15
    const size_t bstride = (size_t)IJ * FQ;   // elements between batches

    #pragma unroll 1
    for (int c = 0; c < CPB; ++c) {
        const int ij = (blockIdx.x * CPB + c) * EPB + g;   // < 40000

        // theta fragment: registers for this chunk (read once)
        const f32x4 t = *reinterpret_cast<const f32x4*>(
            theta + (size_t)ij * FQ + (size_t)s * 4);

        const float* in_base = inp + (size_t)ij * FQ + (size_t)s * 4;
        float* ob = out + ij;

        // reduce-and-store for one quad (current regs a0..a3) at batch b0
        auto crunch = [&](const f32x4& a0, const f32x4& a1,
                          const f32x4& a2, const f32x4& a3, int b0) {
            float p0 = a0.x * t.x + a0.y * t.y + a0.z * t.z + a0.w * t.w;
            float p1 = a1.x * t.x + a1.y * t.y + a1.z * t.z + a1.w * t.w;
            float p2 = a2.x * t.x + a2.y * t.y + a2.z * t.z + a2.w * t.w;
            float p3 = a3.x * t.x + a3.y * t.y + a3.z * t.z + a3.w * t.w;

            p0 += __shfl_xor(p0, 1);  p1 += __shfl_xor(p1, 1);
            p2 += __shfl_xor(p2, 1);  p3 += __shfl_xor(p3, 1);
            p0 += __shfl_xor(p0, 2);  p1 += __shfl_xor(p1, 2);
            p2 += __shfl_xor(p2, 2);  p3 += __shfl_xor(p3, 2);
            p0 += __shfl_xor(p0, 4);  p1 += __shfl_xor(p1, 4);
            p2 += __shfl_xor(p2, 4);  p3 += __shfl_xor(p3, 4);
            p0 += __shfl_xor(p0, 8);  p1 += __shfl_xor(p1, 8);
            p2 += __shfl_xor(p2, 8);  p3 += __shfl_xor(p3, 8);

            if (s == 0) {
                __builtin_nontemporal_store(p0, ob + (size_t)(b0 + 0) * IJ);
                __builtin_nontemporal_store(p1, ob + (size_t)(b0 + 1) * IJ);
                __builtin_nontemporal_store(p2, ob + (size_t)(b0 + 2) * IJ);
                __builtin_nontemporal_store(p3, ob + (size_t)(b0 + 3) * IJ);
            }
        };

        // prologue: first quad in flight
        f32x4 a0 = NTLOAD(in_base + 0 * bstride);
        f32x4 a1 = NTLOAD(in_base + 1 * bstride);
        f32x4 a2 = NTLOAD(in_base + 2 * bstride);
        f32x4 a3 = NTLOAD(in_base + 3 * bstride);

        #pragma unroll 1
        for (int b0 = 0; b0 < BQ - 4; b0 += 4) {
            // issue NEXT quad's loads before reducing the current quad
            const float* nb = in_base + (size_t)(b0 + 4) * bstride;
            const f32x4 n0 = NTLOAD(nb + 0 * bstride);
            const f32x4 n1 = NTLOAD(nb + 1 * bstride);
            const f32x4 n2 = NTLOAD(nb + 2 * bstride);
            const f32x4 n3 = NTLOAD(nb + 3 * bstride);

            crunch(a0, a1, a2, a3, b0);

            a0 = n0; a1 = n1; a2 = n2; a3 = n3;
        }

        // epilogue: last quad (b0 = 60)
        crunch(a0, a1, a2, a3, BQ - 4);
    }
}

extern "C" void kernel_launch(void* const* d_in, const int* in_sizes, int n_in,
                              void* d_out, int out_size, void* d_ws, size_t ws_size,
                              hipStream_t stream) {
    const float* inp   = (const float*)d_in[0];
    const float* theta = (const float*)d_in[1];
    float* out = (float*)d_out;

    IRLLinearModel_42786464203479_kernel<<<GRID, 256, 0, stream>>>(inp, theta, out);
}